// Round 1
// baseline (235.222 us; speedup 1.0000x reference)
//
#include <hip/hip_runtime.h>
#include <hip/hip_bf16.h>
#include <math.h>

typedef unsigned int uint;

// word offsets (4B units) inside the prepared workspace / LDS mirror
#define WB   0      // 4*32*3 packed conv-block weights (bit c = sign>=0 of in-channel c)
#define W1P  384    // 64*16 packed fc1 weights, word [j][i] bit c = sign(fc1_w[j, c*16+i])
#define W2P  1408   // 64*2 packed fc2
#define W3P  1536   // 2 packed fc3
#define SW0  1538   // 32*4 floats: +-1.0 signs of conv0 weights [o][c]
#define SC0  1666   // 32 bn0 scale = g/sqrt(v+eps)
#define M0   1698
#define B0   1730
#define CB0  1762   // conv0_b
#define SCB  1794   // 4*32 block bn scales
#define MB   1922
#define BB   2050
#define CBB  2178   // convs_b
#define SC5  2306
#define M5   2370
#define B5   2434
#define FB1  2498   // fc1_b
#define SC6  2562
#define M6   2626
#define B6   2690
#define FB2  2754   // fc2_b
#define FB3  2818   // fc3_b (1)
#define TOTW 2819

__global__ void prep_kernel(
    const float* __restrict__ conv0_w, const float* __restrict__ conv0_b,
    const float* __restrict__ bn0_g, const float* __restrict__ bn0_b,
    const float* __restrict__ bn0_m, const float* __restrict__ bn0_v,
    const float* __restrict__ convs_w, const float* __restrict__ convs_b,
    const float* __restrict__ bns_g, const float* __restrict__ bns_b,
    const float* __restrict__ bns_m, const float* __restrict__ bns_v,
    const float* __restrict__ fc1_w, const float* __restrict__ fc1_b,
    const float* __restrict__ bn5_g, const float* __restrict__ bn5_b,
    const float* __restrict__ bn5_m, const float* __restrict__ bn5_v,
    const float* __restrict__ fc2_w, const float* __restrict__ fc2_b,
    const float* __restrict__ bn6_g, const float* __restrict__ bn6_b,
    const float* __restrict__ bn6_m, const float* __restrict__ bn6_v,
    const float* __restrict__ fc3_w, const float* __restrict__ fc3_b,
    uint* __restrict__ ws)
{
  const int t = threadIdx.x;
  // packed conv-block weights: [k][o][d], bit c
  for (int u = t; u < 384; u += 256) {
    int k = u / 96, r = u % 96, o = r / 3, d = r % 3;
    uint w = 0;
    for (int c = 0; c < 32; ++c)
      if (convs_w[((k*32 + o)*32 + c)*3 + d] >= 0.f) w |= 1u << c;
    ws[WB + u] = w;
  }
  // packed fc1: [j][i], bit c  (f index k = c*16 + i)
  for (int u = t; u < 1024; u += 256) {
    int j = u >> 4, i = u & 15;
    uint w = 0;
    for (int c = 0; c < 32; ++c)
      if (fc1_w[j*512 + c*16 + i] >= 0.f) w |= 1u << c;
    ws[W1P + u] = w;
  }
  // packed fc2: [j][word]
  for (int u = t; u < 128; u += 256) {
    int j = u >> 1, h = u & 1;
    uint w = 0;
    for (int c = 0; c < 32; ++c)
      if (fc2_w[j*64 + h*32 + c] >= 0.f) w |= 1u << c;
    ws[W2P + u] = w;
  }
  if (t < 2) {
    uint w = 0;
    for (int c = 0; c < 32; ++c)
      if (fc3_w[t*32 + c] >= 0.f) w |= 1u << c;
    ws[W3P + t] = w;
  }
  // conv0 sign weights as +-1.0f ; layout [o][c] (conv0_w is (32,4,1))
  for (int u = t; u < 128; u += 256)
    ws[SW0 + u] = __float_as_uint(conv0_w[u] >= 0.f ? 1.f : -1.f);
  for (int u = t; u < 32; u += 256) {
    ws[SC0 + u] = __float_as_uint(bn0_g[u] / sqrtf(bn0_v[u] + 0.01f));
    ws[M0  + u] = __float_as_uint(bn0_m[u]);
    ws[B0  + u] = __float_as_uint(bn0_b[u]);
    ws[CB0 + u] = __float_as_uint(conv0_b[u]);
  }
  for (int u = t; u < 128; u += 256) {
    ws[SCB + u] = __float_as_uint(bns_g[u] / sqrtf(bns_v[u] + 0.01f));
    ws[MB  + u] = __float_as_uint(bns_m[u]);
    ws[BB  + u] = __float_as_uint(bns_b[u]);
    ws[CBB + u] = __float_as_uint(convs_b[u]);
  }
  for (int u = t; u < 64; u += 256) {
    ws[SC5 + u] = __float_as_uint(bn5_g[u] / sqrtf(bn5_v[u] + 0.01f));
    ws[M5  + u] = __float_as_uint(bn5_m[u]);
    ws[B5  + u] = __float_as_uint(bn5_b[u]);
    ws[FB1 + u] = __float_as_uint(fc1_b[u]);
    ws[SC6 + u] = __float_as_uint(bn6_g[u] / sqrtf(bn6_v[u] + 0.01f));
    ws[M6  + u] = __float_as_uint(bn6_m[u]);
    ws[B6  + u] = __float_as_uint(bn6_b[u]);
    ws[FB2 + u] = __float_as_uint(fc2_b[u]);
  }
  if (t == 0) ws[FB3] = __float_as_uint(fc3_b[0]);
}

__global__ __launch_bounds__(256) void bnn_kernel(const float* __restrict__ x,
                                                  const uint* __restrict__ ws,
                                                  float* __restrict__ out,
                                                  int B)
{
  __shared__ uint sm[TOTW];
  for (int i = threadIdx.x; i < TOTW; i += 256) sm[i] = ws[i];
  __syncthreads();
  const int b = blockIdx.x * 256 + threadIdx.x;
  if (b >= B) return;

#define SMF(idx) __uint_as_float(sm[(idx)])

  // ---- load x[b]: 4 channels x 16 positions ----
  float xr[4][16];
  const float4* xp = (const float4*)(x + (size_t)b * 64);
#pragma unroll
  for (int c = 0; c < 4; ++c) {
#pragma unroll
    for (int q = 0; q < 4; ++q) {
      float4 v = xp[c*4 + q];
      xr[c][q*4+0] = v.x; xr[c][q*4+1] = v.y; xr[c][q*4+2] = v.z; xr[c][q*4+3] = v.w;
    }
  }

  // ---- layer 1: 1x1 binarized conv + bn0 + sign -> s0 bits ----
  uint s0v[16];
#pragma unroll
  for (int i = 0; i < 16; ++i) s0v[i] = 0;
  for (int o = 0; o < 32; ++o) {
    float w0 = SMF(SW0 + o*4 + 0), w1 = SMF(SW0 + o*4 + 1),
          w2 = SMF(SW0 + o*4 + 2), w3 = SMF(SW0 + o*4 + 3);
    float cb = SMF(CB0 + o), mm = SMF(M0 + o), sc = SMF(SC0 + o), bb = SMF(B0 + o);
    uint bit = 1u << o;
#pragma unroll
    for (int i = 0; i < 16; ++i) {
      // sequential c-order, no FMA: bit-exact replication of np einsum + bn
      float d = __fmul_rn(xr[0][i], w0);
      d = __fadd_rn(d, __fmul_rn(xr[1][i], w1));
      d = __fadd_rn(d, __fmul_rn(xr[2][i], w2));
      d = __fadd_rn(d, __fmul_rn(xr[3][i], w3));
      float z = __fadd_rn(d, cb);
      float r = __fadd_rn(__fmul_rn(__fsub_rn(z, mm), sc), bb);
      if (r >= 0.f) s0v[i] |= bit;
    }
  }

  uint cur[16];

  // ---- block 0: conv input = s0 (pure binary) ----
  {
    uint nxt[16];
#pragma unroll
    for (int i = 0; i < 16; ++i) nxt[i] = 0;
    for (int o = 0; o < 32; ++o) {
      uint wa = sm[WB + o*3 + 0], wb = sm[WB + o*3 + 1], wc = sm[WB + o*3 + 2];
      float cb = SMF(CBB + o), mm = SMF(MB + o), sc = SMF(SCB + o), bb = SMF(BB + o);
      uint bit = 1u << o;
#pragma unroll
      for (int p = 0; p < 16; ++p) {
        int pc = __popc(s0v[p] ^ wb);
        int nv = 1;
        if (p > 0)  { pc += __popc(s0v[p-1] ^ wa); ++nv; }
        if (p < 15) { pc += __popc(s0v[p+1] ^ wc); ++nv; }
        int conv = nv*32 - 2*pc;               // exact integer
        float z = __fadd_rn((float)conv, cb);
        float r = __fadd_rn(__fmul_rn(__fsub_rn(z, mm), sc), bb);
        if (r >= 0.f) nxt[p] |= bit;
      }
    }
#pragma unroll
    for (int i = 0; i < 16; ++i) cur[i] = nxt[i];
  }

  // ---- blocks 1..3: conv input = sign(prev) + s0  -> two binary convs ----
  for (int k = 1; k < 4; ++k) {
    uint nxt[16];
#pragma unroll
    for (int i = 0; i < 16; ++i) nxt[i] = 0;
    for (int o = 0; o < 32; ++o) {
      int base = WB + (k*32 + o)*3;
      uint wa = sm[base+0], wb = sm[base+1], wc = sm[base+2];
      float cb = SMF(CBB + k*32 + o), mm = SMF(MB + k*32 + o),
            sc = SMF(SCB + k*32 + o), bb = SMF(BB + k*32 + o);
      uint bit = 1u << o;
#pragma unroll
      for (int p = 0; p < 16; ++p) {
        int pc = __popc(cur[p] ^ wb) + __popc(s0v[p] ^ wb);
        int nv = 1;
        if (p > 0)  { pc += __popc(cur[p-1] ^ wa) + __popc(s0v[p-1] ^ wa); ++nv; }
        if (p < 15) { pc += __popc(cur[p+1] ^ wc) + __popc(s0v[p+1] ^ wc); ++nv; }
        int conv = nv*64 - 2*pc;               // exact integer
        float z = __fadd_rn((float)conv, cb);
        float r = __fadd_rn(__fmul_rn(__fsub_rn(z, mm), sc), bb);
        if (r >= 0.f) nxt[p] |= bit;
      }
    }
#pragma unroll
    for (int i = 0; i < 16; ++i) cur[i] = nxt[i];
  }

  // ---- fc1 (f = cur + s0 ternary) + bn5 + sign ----
  uint h0 = 0, h1 = 0;
  for (int j = 0; j < 64; ++j) {
    int pc = 0;
#pragma unroll
    for (int i = 0; i < 16; ++i) {
      uint ww = sm[W1P + j*16 + i];
      pc += __popc(cur[i] ^ ww) + __popc(s0v[i] ^ ww);
    }
    float z = __fadd_rn((float)(1024 - 2*pc), SMF(FB1 + j));
    float r = __fadd_rn(__fmul_rn(__fsub_rn(z, SMF(M5 + j)), SMF(SC5 + j)), SMF(B5 + j));
    if (r >= 0.f) { if (j < 32) h0 |= 1u << j; else h1 |= 1u << (j - 32); }
  }

  // ---- fc2 + bn6 + sign ----
  uint g0 = 0, g1 = 0;
  for (int j = 0; j < 64; ++j) {
    int pc = __popc(h0 ^ sm[W2P + j*2]) + __popc(h1 ^ sm[W2P + j*2 + 1]);
    float z = __fadd_rn((float)(64 - 2*pc), SMF(FB2 + j));
    float r = __fadd_rn(__fmul_rn(__fsub_rn(z, SMF(M6 + j)), SMF(SC6 + j)), SMF(B6 + j));
    if (r >= 0.f) { if (j < 32) g0 |= 1u << j; else g1 |= 1u << (j - 32); }
  }

  // ---- fc3 + sigmoid ----
  int pc = __popc(g0 ^ sm[W3P]) + __popc(g1 ^ sm[W3P + 1]);
  float z = __fadd_rn((float)(64 - 2*pc), SMF(FB3));
  out[b] = 1.f / (1.f + expf(-z));
#undef SMF
}

extern "C" void kernel_launch(void* const* d_in, const int* in_sizes, int n_in,
                              void* d_out, int out_size, void* d_ws, size_t ws_size,
                              hipStream_t stream) {
  const float* x       = (const float*)d_in[0];
  const float* conv0_w = (const float*)d_in[1];
  const float* conv0_b = (const float*)d_in[2];
  const float* bn0_g   = (const float*)d_in[3];
  const float* bn0_b   = (const float*)d_in[4];
  const float* bn0_m   = (const float*)d_in[5];
  const float* bn0_v   = (const float*)d_in[6];
  const float* convs_w = (const float*)d_in[7];
  const float* convs_b = (const float*)d_in[8];
  const float* bns_g   = (const float*)d_in[9];
  const float* bns_b   = (const float*)d_in[10];
  const float* bns_m   = (const float*)d_in[11];
  const float* bns_v   = (const float*)d_in[12];
  const float* fc1_w   = (const float*)d_in[13];
  const float* fc1_b   = (const float*)d_in[14];
  const float* bn5_g   = (const float*)d_in[15];
  const float* bn5_b   = (const float*)d_in[16];
  const float* bn5_m   = (const float*)d_in[17];
  const float* bn5_v   = (const float*)d_in[18];
  const float* fc2_w   = (const float*)d_in[19];
  const float* fc2_b   = (const float*)d_in[20];
  const float* bn6_g   = (const float*)d_in[21];
  const float* bn6_b   = (const float*)d_in[22];
  const float* bn6_m   = (const float*)d_in[23];
  const float* bn6_v   = (const float*)d_in[24];
  const float* fc3_w   = (const float*)d_in[25];
  const float* fc3_b   = (const float*)d_in[26];
  uint* ws = (uint*)d_ws;

  hipLaunchKernelGGL(prep_kernel, dim3(1), dim3(256), 0, stream,
                     conv0_w, conv0_b, bn0_g, bn0_b, bn0_m, bn0_v,
                     convs_w, convs_b, bns_g, bns_b, bns_m, bns_v,
                     fc1_w, fc1_b, bn5_g, bn5_b, bn5_m, bn5_v,
                     fc2_w, fc2_b, bn6_g, bn6_b, bn6_m, bn6_v,
                     fc3_w, fc3_b, ws);

  const int B = in_sizes[0] / 64;   // 65536
  hipLaunchKernelGGL(bnn_kernel, dim3((B + 255) / 256), dim3(256), 0, stream,
                     x, ws, (float*)d_out, B);
}

// Round 2
// 197.773 us; speedup vs baseline: 1.1894x; 1.1894x over previous
//
#include <hip/hip_runtime.h>
#include <hip/hip_bf16.h>
#include <math.h>

typedef unsigned int uint;

// word offsets (4B units) inside the prepared workspace / LDS mirror
#define WB   0      // 4*32*3 packed conv-block weights (bit c = sign>=0 of in-channel c)
#define W1P  384    // 64*16 packed fc1 weights, word [j][i] bit c = sign(fc1_w[j, c*16+i])
#define W2P  1408   // 64*2 packed fc2
#define W3P  1536   // 2 packed fc3
#define SW0  1538   // 32*4 floats: +-1.0 signs of conv0 weights [o][c]
#define SC0  1666   // 32 bn0 scale = g/sqrt(v+eps)
#define M0   1698
#define B0   1730
#define CB0  1762   // conv0_b
#define SCB  1794   // 4*32 block bn scales
#define MB   1922
#define BB   2050
#define CBB  2178   // convs_b
#define SC5  2306
#define M5   2370
#define B5   2434
#define FB1  2498   // fc1_b
#define SC6  2562
#define M6   2626
#define B6   2690
#define FB2  2754   // fc2_b
#define FB3  2818   // fc3_b (1)
#define TOTW 2819

__global__ void prep_kernel(
    const float* __restrict__ conv0_w, const float* __restrict__ conv0_b,
    const float* __restrict__ bn0_g, const float* __restrict__ bn0_b,
    const float* __restrict__ bn0_m, const float* __restrict__ bn0_v,
    const float* __restrict__ convs_w, const float* __restrict__ convs_b,
    const float* __restrict__ bns_g, const float* __restrict__ bns_b,
    const float* __restrict__ bns_m, const float* __restrict__ bns_v,
    const float* __restrict__ fc1_w, const float* __restrict__ fc1_b,
    const float* __restrict__ bn5_g, const float* __restrict__ bn5_b,
    const float* __restrict__ bn5_m, const float* __restrict__ bn5_v,
    const float* __restrict__ fc2_w, const float* __restrict__ fc2_b,
    const float* __restrict__ bn6_g, const float* __restrict__ bn6_b,
    const float* __restrict__ bn6_m, const float* __restrict__ bn6_v,
    const float* __restrict__ fc3_w, const float* __restrict__ fc3_b,
    uint* __restrict__ ws)
{
  const int t0 = blockIdx.x * blockDim.x + threadIdx.x;
  const int NT = gridDim.x * blockDim.x;
  // packed conv-block weights: [k][o][d], bit c
  for (int u = t0; u < 384; u += NT) {
    int k = u / 96, r = u % 96, o = r / 3, d = r % 3;
    uint w = 0;
    for (int c = 0; c < 32; ++c)
      if (convs_w[((k*32 + o)*32 + c)*3 + d] >= 0.f) w |= 1u << c;
    ws[WB + u] = w;
  }
  // packed fc1: [j][i], bit c  (f index k = c*16 + i)
  for (int u = t0; u < 1024; u += NT) {
    int j = u >> 4, i = u & 15;
    uint w = 0;
    for (int c = 0; c < 32; ++c)
      if (fc1_w[j*512 + c*16 + i] >= 0.f) w |= 1u << c;
    ws[W1P + u] = w;
  }
  // packed fc2: [j][word]
  for (int u = t0; u < 128; u += NT) {
    int j = u >> 1, h = u & 1;
    uint w = 0;
    for (int c = 0; c < 32; ++c)
      if (fc2_w[j*64 + h*32 + c] >= 0.f) w |= 1u << c;
    ws[W2P + u] = w;
  }
  if (t0 < 2) {
    uint w = 0;
    for (int c = 0; c < 32; ++c)
      if (fc3_w[t0*32 + c] >= 0.f) w |= 1u << c;
    ws[W3P + t0] = w;
  }
  // conv0 sign weights as +-1.0f ; layout [o][c] (conv0_w is (32,4,1))
  for (int u = t0; u < 128; u += NT)
    ws[SW0 + u] = __float_as_uint(conv0_w[u] >= 0.f ? 1.f : -1.f);
  for (int u = t0; u < 32; u += NT) {
    ws[SC0 + u] = __float_as_uint(bn0_g[u] / sqrtf(bn0_v[u] + 0.01f));
    ws[M0  + u] = __float_as_uint(bn0_m[u]);
    ws[B0  + u] = __float_as_uint(bn0_b[u]);
    ws[CB0 + u] = __float_as_uint(conv0_b[u]);
  }
  for (int u = t0; u < 128; u += NT) {
    ws[SCB + u] = __float_as_uint(bns_g[u] / sqrtf(bns_v[u] + 0.01f));
    ws[MB  + u] = __float_as_uint(bns_m[u]);
    ws[BB  + u] = __float_as_uint(bns_b[u]);
    ws[CBB + u] = __float_as_uint(convs_b[u]);
  }
  for (int u = t0; u < 64; u += NT) {
    ws[SC5 + u] = __float_as_uint(bn5_g[u] / sqrtf(bn5_v[u] + 0.01f));
    ws[M5  + u] = __float_as_uint(bn5_m[u]);
    ws[B5  + u] = __float_as_uint(bn5_b[u]);
    ws[FB1 + u] = __float_as_uint(fc1_b[u]);
    ws[SC6 + u] = __float_as_uint(bn6_g[u] / sqrtf(bn6_v[u] + 0.01f));
    ws[M6  + u] = __float_as_uint(bn6_m[u]);
    ws[B6  + u] = __float_as_uint(bn6_b[u]);
    ws[FB2 + u] = __float_as_uint(fc2_b[u]);
  }
  if (t0 == 0) ws[FB3] = __float_as_uint(fc3_b[0]);
}

// 4 lanes per sample; lane l owns positions p = 4*l + q, q = 0..3.
__global__ __launch_bounds__(256) void bnn_kernel(const float* __restrict__ x,
                                                  const uint* __restrict__ ws,
                                                  float* __restrict__ out,
                                                  int B)
{
  __shared__ uint sm[TOTW];
  for (int i = threadIdx.x; i < TOTW; i += 256) sm[i] = ws[i];
  __syncthreads();
  const int gt = blockIdx.x * 256 + threadIdx.x;
  const int b  = gt >> 2;
  const int l  = gt & 3;            // sub-lane within sample (positions 4l..4l+3)
  if (b >= B) return;

#define SMF(idx) __uint_as_float(sm[(idx)])

  // ---- load x[b]: 4 channels x 4 owned positions ----
  float xr[4][4];
  const float4* xp = (const float4*)(x + (size_t)b * 64);
#pragma unroll
  for (int c = 0; c < 4; ++c) {
    float4 v = xp[c*4 + l];
    xr[c][0] = v.x; xr[c][1] = v.y; xr[c][2] = v.z; xr[c][3] = v.w;
  }

  // ---- layer 1: 1x1 binarized conv + bn0 + sign -> s0 bits (4 words/lane) ----
  uint s0v[4] = {0, 0, 0, 0};
  for (int o = 0; o < 32; ++o) {
    float w0 = SMF(SW0 + o*4 + 0), w1 = SMF(SW0 + o*4 + 1),
          w2 = SMF(SW0 + o*4 + 2), w3 = SMF(SW0 + o*4 + 3);
    float cb = SMF(CB0 + o), mm = SMF(M0 + o), sc = SMF(SC0 + o), bb = SMF(B0 + o);
    uint bit = 1u << o;
#pragma unroll
    for (int q = 0; q < 4; ++q) {
      // sequential c-order, no FMA: bit-exact replication of np einsum + bn
      float d = __fmul_rn(xr[0][q], w0);
      d = __fadd_rn(d, __fmul_rn(xr[1][q], w1));
      d = __fadd_rn(d, __fmul_rn(xr[2][q], w2));
      d = __fadd_rn(d, __fmul_rn(xr[3][q], w3));
      float z = __fadd_rn(d, cb);
      float r = __fadd_rn(__fmul_rn(__fsub_rn(z, mm), sc), bb);
      if (r >= 0.f) s0v[q] |= bit;
    }
  }

  // static s0 halo words (valid iff l>0 / l<3 respectively)
  const uint s0l = __shfl_up(s0v[3], 1);
  const uint s0r = __shfl_down(s0v[0], 1);
  const bool hasL = (l > 0);
  const bool hasR = (l < 3);

  uint cur[4];

  // ---- block 0: conv input = s0 (pure binary) ----
  {
    uint nxt[4] = {0, 0, 0, 0};
    for (int o = 0; o < 32; ++o) {
      uint wa = sm[WB + o*3 + 0], wb = sm[WB + o*3 + 1], wc = sm[WB + o*3 + 2];
      float cb = SMF(CBB + o), mm = SMF(MB + o), sc = SMF(SCB + o), bb = SMF(BB + o);
      uint bit = 1u << o;
#pragma unroll
      for (int q = 0; q < 4; ++q) {
        int pc = __popc(s0v[q] ^ wb);
        int nv = 1;
        if (q > 0)        { pc += __popc(s0v[q-1] ^ wa); ++nv; }
        else if (hasL)    { pc += __popc(s0l      ^ wa); ++nv; }
        if (q < 3)        { pc += __popc(s0v[q+1] ^ wc); ++nv; }
        else if (hasR)    { pc += __popc(s0r      ^ wc); ++nv; }
        int conv = nv*32 - 2*pc;               // exact integer
        float z = __fadd_rn((float)conv, cb);
        float r = __fadd_rn(__fmul_rn(__fsub_rn(z, mm), sc), bb);
        if (r >= 0.f) nxt[q] |= bit;
      }
    }
#pragma unroll
    for (int q = 0; q < 4; ++q) cur[q] = nxt[q];
  }

  // ---- blocks 1..3: conv input = sign(prev) + s0 (ternary) via agree-mask ----
  // sum_c w_c*(u_c + s_c) = 2*(popc(e) - 2*popc((cur^w)&e)), e = ~(cur^s0)
  for (int k = 1; k < 4; ++k) {
    const uint cl = __shfl_up(cur[3], 1);
    const uint cr = __shfl_down(cur[0], 1);
    uint e[4];
#pragma unroll
    for (int q = 0; q < 4; ++q) e[q] = ~(cur[q] ^ s0v[q]);
    const uint el = ~(cl ^ s0l);
    const uint er = ~(cr ^ s0r);
    int pe0 = __popc(e[0]), pe1 = __popc(e[1]), pe2 = __popc(e[2]), pe3 = __popc(e[3]);
    int pel = hasL ? __popc(el) : 0;
    int per_ = hasR ? __popc(er) : 0;
    int PE[4];
    PE[0] = pel + pe0 + pe1;
    PE[1] = pe0 + pe1 + pe2;
    PE[2] = pe1 + pe2 + pe3;
    PE[3] = pe2 + pe3 + per_;

    uint nxt[4] = {0, 0, 0, 0};
    for (int o = 0; o < 32; ++o) {
      int base = WB + (k*32 + o)*3;
      uint wa = sm[base+0], wb = sm[base+1], wc = sm[base+2];
      float cb = SMF(CBB + k*32 + o), mm = SMF(MB + k*32 + o),
            sc = SMF(SCB + k*32 + o), bb = SMF(BB + k*32 + o);
      uint bit = 1u << o;
#pragma unroll
      for (int q = 0; q < 4; ++q) {
        int pc = __popc((cur[q] ^ wb) & e[q]);
        if (q > 0)      pc += __popc((cur[q-1] ^ wa) & e[q-1]);
        else            pc += hasL ? __popc((cl ^ wa) & el) : 0;
        if (q < 3)      pc += __popc((cur[q+1] ^ wc) & e[q+1]);
        else            pc += hasR ? __popc((cr ^ wc) & er) : 0;
        int conv = 2*(PE[q] - 2*pc);           // exact integer
        float z = __fadd_rn((float)conv, cb);
        float r = __fadd_rn(__fmul_rn(__fsub_rn(z, mm), sc), bb);
        if (r >= 0.f) nxt[q] |= bit;
      }
    }
#pragma unroll
    for (int q = 0; q < 4; ++q) cur[q] = nxt[q];
  }

  // ---- all-gather cur & s0 across the 4-lane group, build agree masks ----
  const int laneid = threadIdx.x & 63;
  const int gbase  = laneid & ~3;
  uint curF[16], eF[16];
  int E = 0;
#pragma unroll
  for (int g = 0; g < 4; ++g) {
#pragma unroll
    for (int q = 0; q < 4; ++q) {
      uint cw = (uint)__shfl((int)cur[q], gbase + g);
      uint sw = (uint)__shfl((int)s0v[q], gbase + g);
      curF[g*4 + q] = cw;
      uint ew = ~(cw ^ sw);
      eF[g*4 + q] = ew;
      E += __popc(ew);
    }
  }

  // ---- fc1 (ternary input) + bn5 + sign : 16 outputs per lane ----
  uint hbits = 0;
  for (int jj = 0; jj < 16; ++jj) {
    int j = (l << 4) | jj;
    int pc = 0;
#pragma unroll
    for (int i = 0; i < 16; ++i) {
      uint ww = sm[W1P + j*16 + i];
      pc += __popc((curF[i] ^ ww) & eF[i]);
    }
    int val = 2*E - 4*pc;                       // exact integer, |val|<=1024
    float z = __fadd_rn((float)val, SMF(FB1 + j));
    float r = __fadd_rn(__fmul_rn(__fsub_rn(z, SMF(M5 + j)), SMF(SC5 + j)), SMF(B5 + j));
    if (r >= 0.f) hbits |= 1u << jj;
  }
  uint h0 = (l == 0) ? hbits : ((l == 1) ? (hbits << 16) : 0u);
  uint h1 = (l == 2) ? hbits : ((l == 3) ? (hbits << 16) : 0u);
  h0 |= (uint)__shfl_xor((int)h0, 1); h0 |= (uint)__shfl_xor((int)h0, 2);
  h1 |= (uint)__shfl_xor((int)h1, 1); h1 |= (uint)__shfl_xor((int)h1, 2);

  // ---- fc2 + bn6 + sign : 16 outputs per lane ----
  uint gbits = 0;
  for (int jj = 0; jj < 16; ++jj) {
    int j = (l << 4) | jj;
    int pc = __popc(h0 ^ sm[W2P + j*2]) + __popc(h1 ^ sm[W2P + j*2 + 1]);
    float z = __fadd_rn((float)(64 - 2*pc), SMF(FB2 + j));
    float r = __fadd_rn(__fmul_rn(__fsub_rn(z, SMF(M6 + j)), SMF(SC6 + j)), SMF(B6 + j));
    if (r >= 0.f) gbits |= 1u << jj;
  }
  uint g0 = (l == 0) ? gbits : ((l == 1) ? (gbits << 16) : 0u);
  uint g1 = (l == 2) ? gbits : ((l == 3) ? (gbits << 16) : 0u);
  g0 |= (uint)__shfl_xor((int)g0, 1); g0 |= (uint)__shfl_xor((int)g0, 2);
  g1 |= (uint)__shfl_xor((int)g1, 1); g1 |= (uint)__shfl_xor((int)g1, 2);

  // ---- fc3 + sigmoid (lane 0 of each group stores) ----
  if (l == 0) {
    int pc = __popc(g0 ^ sm[W3P]) + __popc(g1 ^ sm[W3P + 1]);
    float z = __fadd_rn((float)(64 - 2*pc), SMF(FB3));
    out[b] = 1.f / (1.f + expf(-z));
  }
#undef SMF
}

extern "C" void kernel_launch(void* const* d_in, const int* in_sizes, int n_in,
                              void* d_out, int out_size, void* d_ws, size_t ws_size,
                              hipStream_t stream) {
  const float* x       = (const float*)d_in[0];
  const float* conv0_w = (const float*)d_in[1];
  const float* conv0_b = (const float*)d_in[2];
  const float* bn0_g   = (const float*)d_in[3];
  const float* bn0_b   = (const float*)d_in[4];
  const float* bn0_m   = (const float*)d_in[5];
  const float* bn0_v   = (const float*)d_in[6];
  const float* convs_w = (const float*)d_in[7];
  const float* convs_b = (const float*)d_in[8];
  const float* bns_g   = (const float*)d_in[9];
  const float* bns_b   = (const float*)d_in[10];
  const float* bns_m   = (const float*)d_in[11];
  const float* bns_v   = (const float*)d_in[12];
  const float* fc1_w   = (const float*)d_in[13];
  const float* fc1_b   = (const float*)d_in[14];
  const float* bn5_g   = (const float*)d_in[15];
  const float* bn5_b   = (const float*)d_in[16];
  const float* bn5_m   = (const float*)d_in[17];
  const float* bn5_v   = (const float*)d_in[18];
  const float* fc2_w   = (const float*)d_in[19];
  const float* fc2_b   = (const float*)d_in[20];
  const float* bn6_g   = (const float*)d_in[21];
  const float* bn6_b   = (const float*)d_in[22];
  const float* bn6_m   = (const float*)d_in[23];
  const float* bn6_v   = (const float*)d_in[24];
  const float* fc3_w   = (const float*)d_in[25];
  const float* fc3_b   = (const float*)d_in[26];
  uint* ws = (uint*)d_ws;

  hipLaunchKernelGGL(prep_kernel, dim3(64), dim3(256), 0, stream,
                     conv0_w, conv0_b, bn0_g, bn0_b, bn0_m, bn0_v,
                     convs_w, convs_b, bns_g, bns_b, bns_m, bns_v,
                     fc1_w, fc1_b, bn5_g, bn5_b, bn5_m, bn5_v,
                     fc2_w, fc2_b, bn6_g, bn6_b, bn6_m, bn6_v,
                     fc3_w, fc3_b, ws);

  const int B = in_sizes[0] / 64;   // 65536
  const int threads = B * 4;        // 4 lanes per sample
  hipLaunchKernelGGL(bnn_kernel, dim3((threads + 255) / 256), dim3(256), 0, stream,
                     x, ws, (float*)d_out, B);
}